// Round 7
// baseline (439.148 us; speedup 1.0000x reference)
//
#include <hip/hip_runtime.h>
#include <hip/hip_bf16.h>
#include <stdint.h>

// ReadoutLayer: Wx = x @ W^T (+b cancels under BN), BatchNorm(train) over B*T,
// then ut = a*ut + (1-a)*wxn per t with acc += softmax(ut, axis=H).
// R7 (= R6 with exp2f/log2f instead of __exp2f/__log2f, which collide with glibc
// macros): gemm = register-staged padded LDS (stride 40 els = 4-way conflicts
// ~free; coalesced global loads; single 50KB LDS buffer -> 3 blocks/CU; register
// double-buffer hides global latency under MFMA). Chunk-EWMA aggregate fused into
// gemm epilogue as absolute-weighted sums (w = (1-a)a^(19-pos)) -> 2
// collision-free planes; the standalone agg pass is deleted.

namespace {
constexpr int kB = 32;
constexpr int kT = 2000;
constexpr int kD = 512;
constexpr int kH = 512;
constexpr int kM = kB * kT;     // 64000 rows
constexpr int kL = 20;          // chunk length
constexpr int kC = kT / kL;     // 100 chunks per batch
constexpr int kNC = kB * kC;    // 3200 chunks total (gc = row/20: 2000%20==0)
constexpr float kALo = 0.81873075307798182f;  // exp(-1/5)
constexpr float kAHi = 0.96078943915232320f;  // exp(-1/25)
constexpr int kPad = 40;        // LDS row stride (els): 80B, 16B-aligned, 4-way banks

typedef __bf16 bf16x8 __attribute__((ext_vector_type(8)));
typedef float floatx16 __attribute__((ext_vector_type(16)));

__device__ __forceinline__ float bf2f(unsigned short u) {
  return __builtin_bit_cast(float, (unsigned)u << 16);
}
__device__ __forceinline__ float clipa(float a) {
  return fminf(fmaxf(a, kALo), kAHi);
}
__device__ __forceinline__ float pow20(float a) {
  const float a2 = a * a, a4 = a2 * a2, a5 = a4 * a;
  const float a10 = a5 * a5;
  return a10 * a10;
}

// ---------- K0: W f32 -> bf16 ----------
__global__ __launch_bounds__(256) void wcvt_k(const float* __restrict__ W,
                                              __bf16* __restrict__ Wbf) {
  const int t = blockIdx.x * 256 + threadIdx.x;
  const float4 a0 = ((const float4*)W)[t * 2];
  const float4 a1 = ((const float4*)W)[t * 2 + 1];
  bf16x8 v;
  v[0] = (__bf16)a0.x; v[1] = (__bf16)a0.y; v[2] = (__bf16)a0.z; v[3] = (__bf16)a0.w;
  v[4] = (__bf16)a1.x; v[5] = (__bf16)a1.y; v[6] = (__bf16)a1.z; v[7] = (__bf16)a1.w;
  *(bf16x8*)(Wbf + (size_t)t * 8) = v;
}

// ---------- K1: GEMM 64 rows x 512 cols per block + fused BN stats + fused chunk agg ----------
// 8 waves; wave w: row-tile rt=w>>2 (32 rows), col-tiles ct0=(w&3)*4 .. +4.
__global__ __launch_bounds__(512, 4) void gemm_k(const float* __restrict__ X,
                                                 const __bf16* __restrict__ Wbf,
                                                 const float* __restrict__ alpha,
                                                 unsigned short* __restrict__ Wxb,
                                                 float* __restrict__ partial,
                                                 float* __restrict__ vplanes) {
  __shared__ __align__(16) __bf16 As[64][kPad];    // 5.0 KB
  __shared__ __align__(16) __bf16 Bs[512][kPad];   // 40 KB
  __shared__ float sred[2][kH];                    // 4 KB  -> total 50176 B
  float* aggLds = (float*)&Bs[0][0];               // [4][512] overlay (post-K-loop)

  const int tid = threadIdx.x;
  const int r0i = blockIdx.x * 64;
  const size_t row0 = (size_t)r0i;
  const int w = tid >> 6, L = tid & 63;
  const int rt = w >> 2, ct0 = (w & 3) * 4;
  const int lhalf = L >> 5, l32 = L & 31;
  const int am = tid >> 2, akq = tid & 3;   // A staging (threads 0..255)
  const int bn = tid >> 2, bkq = tid & 3;   // B staging: rows bn+128j

  floatx16 acc[4] = {};
  float4 ap0, ap1;
  uint4 br[4];

  auto loadA = [&](int s) {
    if (tid < 256) {
      const float4* p = (const float4*)(X + (row0 + am) * kD + s * 32 + akq * 8);
      ap0 = p[0]; ap1 = p[1];
    }
  };
  auto loadB = [&](int s) {
#pragma unroll
    for (int j = 0; j < 4; ++j)
      br[j] = *(const uint4*)(Wbf + (size_t)(bn + 128 * j) * kD + s * 32 + bkq * 8);
  };
  auto storeLds = [&]() {
    if (tid < 256) {
      bf16x8 v;
      v[0] = (__bf16)ap0.x; v[1] = (__bf16)ap0.y; v[2] = (__bf16)ap0.z; v[3] = (__bf16)ap0.w;
      v[4] = (__bf16)ap1.x; v[5] = (__bf16)ap1.y; v[6] = (__bf16)ap1.z; v[7] = (__bf16)ap1.w;
      *(bf16x8*)&As[am][akq * 8] = v;
    }
#pragma unroll
    for (int j = 0; j < 4; ++j)
      *(uint4*)&Bs[bn + 128 * j][bkq * 8] = br[j];
  };

  loadA(0);
  loadB(0);
#pragma unroll 1
  for (int s = 0; s < 16; ++s) {
    storeLds();
    __syncthreads();
    if (s < 15) { loadA(s + 1); loadB(s + 1); }  // reg dbuf: overlaps MFMA phase
#pragma unroll
    for (int kh = 0; kh < 2; ++kh) {
      const bf16x8 af = *(const bf16x8*)&As[rt * 32 + l32][kh * 16 + lhalf * 8];
#pragma unroll
      for (int c = 0; c < 4; ++c) {
        const bf16x8 bfr = *(const bf16x8*)&Bs[(ct0 + c) * 32 + l32][kh * 16 + lhalf * 8];
        acc[c] = __builtin_amdgcn_mfma_f32_32x32x16_bf16(af, bfr, acc[c], 0, 0, 0);
      }
    }
    __syncthreads();
  }

  // ---- epilogue: zero LDS accumulators (Bs is dead now) ----
  sred[0][tid] = 0.f;
  sred[1][tid] = 0.f;
  aggLds[tid] = 0.f; aggLds[512 + tid] = 0.f;
  aggLds[1024 + tid] = 0.f; aggLds[1536 + tid] = 0.f;
  __syncthreads();

  // ---- BN stats (LDS atomics) ----
#pragma unroll
  for (int c = 0; c < 4; ++c) {
    float s = 0.f, q = 0.f;
#pragma unroll
    for (int r = 0; r < 16; ++r) {
      const float v = acc[c][r];
      s += v; q += v * v;
    }
    s += __shfl_xor(s, 32);
    q += __shfl_xor(q, 32);
    if (lhalf == 0) {
      atomicAdd(&sred[0][(ct0 + c) * 32 + l32], s);
      atomicAdd(&sred[1][(ct0 + c) * 32 + l32], q);
    }
  }

  // ---- fused chunk-EWMA partials: weight = (1-a) * a^(19-pos), slot = chunk idx ----
  // C/D: col = lane&31, row = 4*lhalf + (r&3) + 8*(r>>2) (+32*rt)
  const int r0m = r0i % 20;
  const int gc0 = r0i / 20;
  const int s_base = r0m + rt * 32 + 4 * lhalf;  // 0..52; +off(r) <= 79 -> 4 slots
#pragma unroll
  for (int c = 0; c < 4; ++c) {
    const int h = (ct0 + c) * 32 + l32;
    const float a = clipa(alpha[h]);
    const float la = log2f(a);
    const float oma = 1.0f - a;
    float q0 = 0.f, q1 = 0.f, q2 = 0.f, q3 = 0.f;
#pragma unroll
    for (int r = 0; r < 16; ++r) {
      const int off = (r & 3) + 8 * (r >> 2);
      const int sf = s_base + off;          // absolute (row - chunk-grid) offset
      const int slot = sf / 20;             // 0..3
      const int e = 19 + slot * 20 - sf;    // 19 - pos
      const float cv = acc[c][r] * oma * exp2f((float)e * la);
      q0 += (slot == 0) ? cv : 0.f;
      q1 += (slot == 1) ? cv : 0.f;
      q2 += (slot == 2) ? cv : 0.f;
      q3 += (slot == 3) ? cv : 0.f;
    }
    q0 += __shfl_xor(q0, 32); q1 += __shfl_xor(q1, 32);
    q2 += __shfl_xor(q2, 32); q3 += __shfl_xor(q3, 32);
    if (lhalf == 0) {  // 32 consecutive h per instr: conflict-free LDS atomics
      atomicAdd(&aggLds[h], q0);
      atomicAdd(&aggLds[512 + h], q1);
      atomicAdd(&aggLds[1024 + h], q2);
      atomicAdd(&aggLds[1536 + h], q3);
    }
  }

  // ---- store Wx bf16 (packed dword pairs via shfl) ----
#pragma unroll
  for (int c = 0; c < 4; ++c) {
    const int col = (ct0 + c) * 32 + l32;
#pragma unroll
    for (int r = 0; r < 16; ++r) {
      const int row = rt * 32 + 4 * lhalf + (r & 3) + 8 * (r >> 2);
      const unsigned short u = __builtin_bit_cast(unsigned short, (__bf16)acc[c][r]);
      const unsigned un = __shfl_down((unsigned)u, 1);
      if ((l32 & 1) == 0)
        *(unsigned*)(Wxb + (row0 + row) * (size_t)kH + col) = (unsigned)u | (un << 16);
    }
  }
  __syncthreads();
  // ---- plane writes: slot 0 straddles (started in prev block) -> plane 1 ----
#pragma unroll
  for (int s = 0; s < 4; ++s) {
    const int gcs = gc0 + s;
    const int pl = (s == 0 && r0m != 0) ? 1 : 0;
    vplanes[(size_t)pl * kNC * kH + (size_t)gcs * kH + tid] = aggLds[s * 512 + tid];
  }
  partial[(size_t)blockIdx.x * 1024 + tid] = sred[0][tid];
  partial[(size_t)blockIdx.x * 1024 + 512 + tid] = sred[1][tid];
}

// ---------- K2: reduce per-block stat partials 1000 -> 40 ----------
__global__ __launch_bounds__(512) void red1_k(const float* __restrict__ partial,
                                              float* __restrict__ partial2) {
  const int tid = threadIdx.x;
  const int r0 = blockIdx.x * 25;
  float s0 = 0.f, s1 = 0.f;
#pragma unroll 5
  for (int r = 0; r < 25; ++r) {
    s0 += partial[(size_t)(r0 + r) * 1024 + tid];
    s1 += partial[(size_t)(r0 + r) * 1024 + 512 + tid];
  }
  partial2[(size_t)blockIdx.x * 1024 + tid] = s0;
  partial2[(size_t)blockIdx.x * 1024 + 512 + tid] = s1;
}

// ---------- K3: finalize BN scale/shift + alpha params ----------
// prm: [0]=scale [512]=shift [1024]=a [1536]=1-a [2048]=a^L
__global__ __launch_bounds__(512) void finalize_k(const float* __restrict__ partial2,
                                                  const float* __restrict__ alpha,
                                                  const float* __restrict__ gamma,
                                                  const float* __restrict__ beta,
                                                  float* __restrict__ prm) {
  const int h = threadIdx.x;
  float s0 = 0.f, s1 = 0.f;
#pragma unroll 8
  for (int r = 0; r < 40; ++r) {
    s0 += partial2[(size_t)r * 1024 + h];
    s1 += partial2[(size_t)r * 1024 + 512 + h];
  }
  const float inv_n = 1.0f / (float)kM;
  const float mean = s0 * inv_n;
  const float var = s1 * inv_n - mean * mean;
  const float sc = gamma[h] * rsqrtf(var + 1e-5f);
  const float sh = beta[h] - mean * sc;
  const float a = clipa(alpha[h]);
  prm[h] = sc;
  prm[kH + h] = sh;
  prm[2 * kH + h] = a;
  prm[3 * kH + h] = 1.0f - a;
  prm[4 * kH + h] = pow20(a);
}

// ---------- K4: chunk-boundary scan; v_c = plane0+plane1; BN folded ----------
// u' = a^20 u + sc*v_raw + sh*(1-a^20); plane0 overwritten in-place with ustart.
__global__ __launch_bounds__(512) void scan_k(const float* __restrict__ ut0,
                                              const float* __restrict__ alpha,
                                              const float* __restrict__ prm,
                                              float* __restrict__ vplanes) {
  const int b = blockIdx.x;
  const int h = threadIdx.x;
  const float a20 = pow20(clipa(alpha[h]));
  const float sc = prm[h];
  const float shc = prm[kH + h] * (1.0f - a20);
  const float* p1 = vplanes + (size_t)kNC * kH;
  float u = ut0[(size_t)b * kH + h];
  float vc[10];
#pragma unroll 1
  for (int cb = 0; cb < kC; cb += 10) {
#pragma unroll
    for (int j = 0; j < 10; ++j) {
      const size_t idx = ((size_t)b * kC + cb + j) * kH + h;
      vc[j] = vplanes[idx] + p1[idx];  // independent, pipelined
    }
#pragma unroll
    for (int j = 0; j < 10; ++j) {
      vplanes[((size_t)b * kC + cb + j) * kH + h] = u;  // ustart for chunk
      u = a20 * u + sc * vc[j] + shc;
    }
  }
}

// ---------- K5: per-chunk softmax accumulation, 4 h per thread ----------
__global__ __launch_bounds__(128) void soft_k(const unsigned short* __restrict__ Wxb,
                                              const float* __restrict__ prm,
                                              const float* __restrict__ ustart,
                                              float* __restrict__ accp) {
  __shared__ float part[kL][2];
  __shared__ float zinv[kL];
  const int bc = blockIdx.x;
  const int b = bc / kC, c = bc % kC;
  const int t = threadIdx.x;
  const int wv = t >> 6, lane = t & 63;
  const int h0 = t * 4;
  const float4 sc = *(const float4*)(prm + h0);
  const float4 sh = *(const float4*)(prm + kH + h0);
  const float4 aa = *(const float4*)(prm + 2 * kH + h0);
  const float4 om = *(const float4*)(prm + 3 * kH + h0);
  float4 u = *(const float4*)(ustart + (size_t)bc * kH + h0);
  const unsigned short* base = Wxb + ((size_t)b * kT + (size_t)c * kL) * kH + h0;
  float e[kL][4];
#pragma unroll
  for (int i = 0; i < kL; ++i) {
    const uint2 p = *(const uint2*)(base + (size_t)i * kH);
    const float w0 = bf2f((unsigned short)(p.x & 0xffff)) * sc.x + sh.x;
    const float w1 = bf2f((unsigned short)(p.x >> 16)) * sc.y + sh.y;
    const float w2 = bf2f((unsigned short)(p.y & 0xffff)) * sc.z + sh.z;
    const float w3 = bf2f((unsigned short)(p.y >> 16)) * sc.w + sh.w;
    u.x = aa.x * u.x + om.x * w0;
    u.y = aa.y * u.y + om.y * w1;
    u.z = aa.z * u.z + om.z * w2;
    u.w = aa.w * u.w + om.w * w3;
    e[i][0] = __expf(u.x); e[i][1] = __expf(u.y);
    e[i][2] = __expf(u.z); e[i][3] = __expf(u.w);
    float s = (e[i][0] + e[i][1]) + (e[i][2] + e[i][3]);
#pragma unroll
    for (int off = 32; off > 0; off >>= 1) s += __shfl_xor(s, off);
    if (lane == 0) part[i][wv] = s;
  }
  __syncthreads();
  if (t < kL) zinv[t] = 1.0f / (part[t][0] + part[t][1]);
  __syncthreads();
  float4 o = make_float4(0.f, 0.f, 0.f, 0.f);
#pragma unroll
  for (int i = 0; i < kL; ++i) {
    const float z = zinv[i];
    o.x += e[i][0] * z; o.y += e[i][1] * z;
    o.z += e[i][2] * z; o.w += e[i][3] * z;
  }
  *(float4*)(accp + (size_t)bc * kH + h0) = o;
}

// ---------- K6: reduce chunk partials -> out ----------
__global__ __launch_bounds__(128) void out_red_k(const float* __restrict__ accp,
                                                 float* __restrict__ out) {
  const int b = blockIdx.x >> 2, q = blockIdx.x & 3;
  const int h = q * 128 + threadIdx.x;
  float s = 0.f;
#pragma unroll 5
  for (int c = 0; c < kC; ++c) s += accp[((size_t)b * kC + c) * kH + h];
  out[(size_t)b * kH + h] = s;
}

}  // namespace

extern "C" void kernel_launch(void* const* d_in, const int* in_sizes, int n_in,
                              void* d_out, int out_size, void* d_ws, size_t ws_size,
                              hipStream_t stream) {
  const float* x = (const float*)d_in[0];      // [32,2000,512]
  const float* Wm = (const float*)d_in[1];     // [512,512]
  // d_in[2] = b: unused — BN mean subtraction cancels the bias exactly
  const float* alpha = (const float*)d_in[3];
  const float* gamma = (const float*)d_in[4];
  const float* beta = (const float*)d_in[5];
  const float* ut0 = (const float*)d_in[6];
  float* out = (float*)d_out;                  // [32,1,512]

  float* wsp = (float*)d_ws;
  float* vplanes = wsp;                                // 2*3200*512 f (13.1 MB)
  float* accp = vplanes + (size_t)2 * kNC * kH;        // 3200*512 f
  float* partial = accp + (size_t)kNC * kH;            // 1000*1024 f
  float* partial2 = partial + (size_t)1000 * 1024;     // 40*1024 f
  float* prm = partial2 + (size_t)40 * 1024;           // 2560 f
  __bf16* Wbf = (__bf16*)(prm + 5 * kH);               // 262144 bf16 (16B-aligned)
  unsigned short* Wxb = (unsigned short*)(Wbf + (size_t)kH * kD);  // 65.5 MB

  // plane1 must be zero for chunks with no straddle writer
  (void)hipMemsetAsync(vplanes + (size_t)kNC * kH, 0, (size_t)kNC * kH * sizeof(float), stream);
  wcvt_k<<<128, 256, 0, stream>>>(Wm, Wbf);
  gemm_k<<<kM / 64, 512, 0, stream>>>(x, Wbf, alpha, Wxb, partial, vplanes);
  red1_k<<<40, 512, 0, stream>>>(partial, partial2);
  finalize_k<<<1, 512, 0, stream>>>(partial2, alpha, gamma, beta, prm);
  scan_k<<<kB, 512, 0, stream>>>(ut0, alpha, prm, vplanes);
  soft_k<<<kNC, 128, 0, stream>>>(Wxb, prm, vplanes, accp);
  out_red_k<<<kB * 4, 128, 0, stream>>>(accp, out);
}